// Round 3
// baseline (5096.009 us; speedup 1.0000x reference)
//
#include <hip/hip_runtime.h>
#include <hip/hip_bf16.h>

// FPS: B=64, N=32768, C=3, S=1024.
// One block per batch; 1024 threads; 32 points/thread; min-dist in registers.
//
// Exactness: the harness needs a bit-exact index trajectory vs the XLA-CPU
// reference. XLA CPU (fast-math) contracts the distance sum into FMAs as:
//     d = fma(dz, dz, fma(dx, dx, dy*dy))
// (DAGCombiner fuses fadd(fmul,fmul) via operand-0 first, then the trailing
// mul). We reproduce that exact op sequence with __builtin_fmaf; all other
// FP stays uncontracted RN via the clang fp pragma.
// argmax = first occurrence (strict > in ascending index, min-index ties).

#define FPS_N 32768
#define FPS_S 1024
#define FPS_NT 1024
#define FPS_P (FPS_N / FPS_NT)   // 32 points per thread

__global__ __launch_bounds__(FPS_NT) void FPSModel_80753975099708_kernel(
    const float* __restrict__ x,   // [B, N, 3]
    float* __restrict__ out_pts,   // [B, S, 3]
    float* __restrict__ out_idx)   // [B, S] (indices stored as float values)
{
#pragma clang fp contract(off)
    const int b = blockIdx.x;
    const int t = threadIdx.x;
    const float* __restrict__ xb = x + (size_t)b * FPS_N * 3;
    float* __restrict__ op = out_pts + (size_t)b * FPS_S * 3;
    float* __restrict__ oi = out_idx + (size_t)b * FPS_S;

    // double-buffered per-wave reduction slots: (value, index-bits)
    __shared__ float2 red[2][FPS_NT / 64];

    float mind[FPS_P];
#pragma unroll
    for (int k = 0; k < FPS_P; ++k) mind[k] = __int_as_float(0x7f800000); // +inf

    int cur = 0;
    if (t == 0) {
        oi[0] = 0.0f;
        op[0] = xb[0];
        op[1] = xb[1];
        op[2] = xb[2];
    }

    for (int s = 1; s < FPS_S; ++s) {
        const float px = xb[(size_t)cur * 3 + 0];
        const float py = xb[(size_t)cur * 3 + 1];
        const float pz = xb[(size_t)cur * 3 + 2];

        float bestv = __int_as_float(0xff800000); // -inf
        int   besti = 0x7fffffff;

#pragma unroll
        for (int k = 0; k < FPS_P; ++k) {
            const int i = k * FPS_NT + t;               // ascending index in k
            const float* __restrict__ p = xb + (size_t)i * 3;
            const float dx = p[0] - px;
            const float dy = p[1] - py;
            const float dz = p[2] - pz;
            // XLA-CPU contracted form: fma(dz,dz, fma(dx,dx, dy*dy))
            const float dyy = dy * dy;                       // plain RN mul
            const float u   = __builtin_fmaf(dx, dx, dyy);   // fused
            const float d   = __builtin_fmaf(dz, dz, u);     // fused
            const float m = fminf(mind[k], d);
            mind[k] = m;
            // strict > keeps the smallest index among equal maxima
            if (m > bestv) { bestv = m; besti = i; }
        }

        // Wave-level butterfly reduce (64 lanes), tie-break to smaller index.
#pragma unroll
        for (int off = 32; off; off >>= 1) {
            const float ov = __shfl_xor(bestv, off);
            const int   ob = __shfl_xor(besti, off);
            if (ov > bestv || (ov == bestv && ob < besti)) { bestv = ov; besti = ob; }
        }

        const int wave = t >> 6;
        if ((t & 63) == 0) {
            red[s & 1][wave] = make_float2(bestv, __int_as_float(besti));
        }
        __syncthreads();

        // Every thread reduces the 16 wave results identically.
        float gv = __int_as_float(0xff800000);
        int   gi = 0x7fffffff;
#pragma unroll
        for (int w = 0; w < FPS_NT / 64; ++w) {
            const float2 e = red[s & 1][w];
            const int ei = __float_as_int(e.y);
            if (e.x > gv || (e.x == gv && ei < gi)) { gv = e.x; gi = ei; }
        }
        cur = gi;

        if (t == 0) {
            oi[s] = (float)cur;
            const float* __restrict__ p = xb + (size_t)cur * 3;
            op[(size_t)s * 3 + 0] = p[0];
            op[(size_t)s * 3 + 1] = p[1];
            op[(size_t)s * 3 + 2] = p[2];
        }
    }
}

extern "C" void kernel_launch(void* const* d_in, const int* in_sizes, int n_in,
                              void* d_out, int out_size, void* d_ws, size_t ws_size,
                              hipStream_t stream) {
    const float* x = (const float*)d_in[0];
    const int B = in_sizes[0] / (FPS_N * 3);

    float* out_pts = (float*)d_out;
    float* out_idx = out_pts + (size_t)B * FPS_S * 3;

    hipLaunchKernelGGL(FPSModel_80753975099708_kernel,
                       dim3(B), dim3(FPS_NT), 0, stream,
                       x, out_pts, out_idx);
}

// Round 4
// 4276.290 us; speedup vs baseline: 1.1917x; 1.1917x over previous
//
#include <hip/hip_runtime.h>
#include <hip/hip_bf16.h>

// FPS: B=64, N=32768, C=3, S=1024. One block per batch, 1024 threads,
// 32 points/thread.
//
// Round-4 structure: the main loop does ZERO global-memory traffic for the
// point cloud. Per thread: x,y coords (64 VGPRs) + running min-dist (32
// VGPRs) live in registers (fully unrolled, static indices only); the z
// plane lives in LDS (131 KB of 160 KB), layout z[k*1024 + t] so a wave's
// 64 lanes hit consecutive banks (2-way aliasing = free). Only remaining
// global access per step is the 12 B broadcast read of the current point.
//
// Exactness (bit-exact trajectory vs XLA-CPU reference, validated round 3):
//   d = fma(dz,dz, fma(dx,dx, dy*dy)), fminf running min,
//   first-occurrence argmax (strict >, ascending index; min index on ties).

#define FPS_N 32768
#define FPS_S 1024
#define FPS_NT 1024
#define FPS_P (FPS_N / FPS_NT)   // 32 points per thread

__global__ __launch_bounds__(FPS_NT) void FPSModel_80753975099708_kernel(
    const float* __restrict__ x,   // [B, N, 3]
    float* __restrict__ out_pts,   // [B, S, 3]
    float* __restrict__ out_idx)   // [B, S] (indices stored as float values)
{
#pragma clang fp contract(off)
    const int b = blockIdx.x;
    const int t = threadIdx.x;
    const float* __restrict__ xb = x + (size_t)b * FPS_N * 3;
    float* __restrict__ op = out_pts + (size_t)b * FPS_S * 3;
    float* __restrict__ oi = out_idx + (size_t)b * FPS_S;

    __shared__ float zsh[FPS_N];                 // z plane: 131072 B
    __shared__ float2 red[2][FPS_NT / 64];       // per-wave (value, idx-bits)

    float cx[FPS_P], cy[FPS_P], mind[FPS_P];

    // Prologue: stage coords. x,y -> registers; z -> LDS. One-time cost.
#pragma unroll
    for (int k = 0; k < FPS_P; ++k) {
        const int i = k * FPS_NT + t;
        const float* __restrict__ p = xb + (size_t)i * 3;
        cx[k] = p[0];
        cy[k] = p[1];
        zsh[i] = p[2];
        mind[k] = __int_as_float(0x7f800000);    // +inf
    }

    int cur = 0;
    if (t == 0) {
        oi[0] = 0.0f;
        op[0] = xb[0];
        op[1] = xb[1];
        op[2] = xb[2];
    }
    __syncthreads();                             // zsh visible to all waves

    for (int s = 1; s < FPS_S; ++s) {
        // Broadcast read of current farthest point (one 12 B L1/L2 line).
        const float px = xb[(size_t)cur * 3 + 0];
        const float py = xb[(size_t)cur * 3 + 1];
        const float pz = xb[(size_t)cur * 3 + 2];

        float bestv = __int_as_float(0xff800000); // -inf
        int   bestk = 0;                          // i = bestk*1024 + t

#pragma unroll
        for (int k = 0; k < FPS_P; ++k) {
            const float dx = cx[k] - px;
            const float dy = cy[k] - py;
            const float dz = zsh[k * FPS_NT + t] - pz;
            // XLA-CPU contracted form: fma(dz,dz, fma(dx,dx, dy*dy))
            const float dyy = dy * dy;
            const float u   = __builtin_fmaf(dx, dx, dyy);
            const float d   = __builtin_fmaf(dz, dz, u);
            const float m = fminf(mind[k], d);
            mind[k] = m;
            // strict > keeps the smallest k among equal maxima (k ascending)
            if (m > bestv) { bestv = m; bestk = k; }
        }
        int besti = bestk * FPS_NT + t;

        // Wave-level butterfly reduce (64 lanes), tie-break to smaller index.
#pragma unroll
        for (int off = 32; off; off >>= 1) {
            const float ov = __shfl_xor(bestv, off);
            const int   ob = __shfl_xor(besti, off);
            if (ov > bestv || (ov == bestv && ob < besti)) { bestv = ov; besti = ob; }
        }

        const int wave = t >> 6;
        if ((t & 63) == 0) {
            red[s & 1][wave] = make_float2(bestv, __int_as_float(besti));
        }
        __syncthreads();

        // Every thread reduces the 16 wave slots identically (broadcast LDS
        // reads); double-buffered red[] makes next iteration's writes safe.
        float gv = __int_as_float(0xff800000);
        int   gi = 0x7fffffff;
#pragma unroll
        for (int w = 0; w < FPS_NT / 64; ++w) {
            const float2 e = red[s & 1][w];
            const int ei = __float_as_int(e.y);
            if (e.x > gv || (e.x == gv && ei < gi)) { gv = e.x; gi = ei; }
        }
        cur = gi;

        if (t == 0) {
            oi[s] = (float)cur;
            const float* __restrict__ p = xb + (size_t)cur * 3;
            op[(size_t)s * 3 + 0] = p[0];
            op[(size_t)s * 3 + 1] = p[1];
            op[(size_t)s * 3 + 2] = p[2];
        }
    }
}

extern "C" void kernel_launch(void* const* d_in, const int* in_sizes, int n_in,
                              void* d_out, int out_size, void* d_ws, size_t ws_size,
                              hipStream_t stream) {
    const float* x = (const float*)d_in[0];
    const int B = in_sizes[0] / (FPS_N * 3);

    float* out_pts = (float*)d_out;
    float* out_idx = out_pts + (size_t)B * FPS_S * 3;

    hipLaunchKernelGGL(FPSModel_80753975099708_kernel,
                       dim3(B), dim3(FPS_NT), 0, stream,
                       x, out_pts, out_idx);
}

// Round 5
// 3765.901 us; speedup vs baseline: 1.3532x; 1.1355x over previous
//
#include <hip/hip_runtime.h>
#include <hip/hip_bf16.h>

// FPS: B=64, N=32768, C=3, S=1024. One block per batch, 1024 threads,
// 32 points/thread.
//
// Round-5: round 4's intent (x,y in VGPRs, z in LDS) was defeated by the
// compiler: VGPR_Count=64 < the 96 needed => it rematerialized cx/cy by
// re-reading global every step (legal: x is const __restrict__). Fixes:
//   (a) __launch_bounds__(1024, 4): allow 128 VGPRs/thread (LDS already
//       limits us to 1 block/CU, so this costs nothing).
//   (b) asm volatile "+v" pin on cx[k], cy[k] after the prologue load:
//       origin becomes opaque -> no remat-by-reload, values stay in VGPRs.
//
// Exactness (bit-exact trajectory vs XLA-CPU reference, validated round 3):
//   d = fma(dz,dz, fma(dx,dx, dy*dy)), fminf running min,
//   first-occurrence argmax (strict >, ascending index; min index on ties).

#define FPS_N 32768
#define FPS_S 1024
#define FPS_NT 1024
#define FPS_P (FPS_N / FPS_NT)   // 32 points per thread

__global__ __launch_bounds__(FPS_NT, 4) void FPSModel_80753975099708_kernel(
    const float* __restrict__ x,   // [B, N, 3]
    float* __restrict__ out_pts,   // [B, S, 3]
    float* __restrict__ out_idx)   // [B, S] (indices stored as float values)
{
#pragma clang fp contract(off)
    const int b = blockIdx.x;
    const int t = threadIdx.x;
    const float* __restrict__ xb = x + (size_t)b * FPS_N * 3;
    float* __restrict__ op = out_pts + (size_t)b * FPS_S * 3;
    float* __restrict__ oi = out_idx + (size_t)b * FPS_S;

    __shared__ float zsh[FPS_N];                 // z plane: 131072 B
    __shared__ float2 red[2][FPS_NT / 64];       // per-wave (value, idx-bits)

    float cx[FPS_P], cy[FPS_P], mind[FPS_P];

    // Prologue: stage coords. x,y -> registers (pinned); z -> LDS.
#pragma unroll
    for (int k = 0; k < FPS_P; ++k) {
        const int i = k * FPS_NT + t;
        const float* __restrict__ p = xb + (size_t)i * 3;
        cx[k] = p[0];
        cy[k] = p[1];
        zsh[i] = p[2];
        // Opaque touch: compiler must keep cx/cy as live VGPR values
        // (cannot fold the global load back into each step's use).
        asm volatile("" : "+v"(cx[k]), "+v"(cy[k]));
        mind[k] = __int_as_float(0x7f800000);    // +inf
    }

    int cur = 0;
    if (t == 0) {
        oi[0] = 0.0f;
        op[0] = xb[0];
        op[1] = xb[1];
        op[2] = xb[2];
    }
    __syncthreads();                             // zsh visible to all waves

    for (int s = 1; s < FPS_S; ++s) {
        // Broadcast read of current farthest point (12 B, L2-resident).
        const float px = xb[(size_t)cur * 3 + 0];
        const float py = xb[(size_t)cur * 3 + 1];
        const float pz = xb[(size_t)cur * 3 + 2];

        float bestv = __int_as_float(0xff800000); // -inf
        int   bestk = 0;                          // i = bestk*1024 + t

#pragma unroll
        for (int k = 0; k < FPS_P; ++k) {
            const float dx = cx[k] - px;
            const float dy = cy[k] - py;
            const float dz = zsh[k * FPS_NT + t] - pz;
            // XLA-CPU contracted form: fma(dz,dz, fma(dx,dx, dy*dy))
            const float dyy = dy * dy;
            const float u   = __builtin_fmaf(dx, dx, dyy);
            const float d   = __builtin_fmaf(dz, dz, u);
            const float m = fminf(mind[k], d);
            mind[k] = m;
            // strict > keeps the smallest k among equal maxima (k ascending)
            if (m > bestv) { bestv = m; bestk = k; }
        }
        int besti = bestk * FPS_NT + t;

        // Wave-level butterfly reduce (64 lanes), tie-break to smaller index.
#pragma unroll
        for (int off = 32; off; off >>= 1) {
            const float ov = __shfl_xor(bestv, off);
            const int   ob = __shfl_xor(besti, off);
            if (ov > bestv || (ov == bestv && ob < besti)) { bestv = ov; besti = ob; }
        }

        const int wave = t >> 6;
        if ((t & 63) == 0) {
            red[s & 1][wave] = make_float2(bestv, __int_as_float(besti));
        }
        __syncthreads();

        // Every thread reduces the 16 wave slots identically (broadcast LDS
        // reads); double-buffered red[] makes next iteration's writes safe.
        float gv = __int_as_float(0xff800000);
        int   gi = 0x7fffffff;
#pragma unroll
        for (int w = 0; w < FPS_NT / 64; ++w) {
            const float2 e = red[s & 1][w];
            const int ei = __float_as_int(e.y);
            if (e.x > gv || (e.x == gv && ei < gi)) { gv = e.x; gi = ei; }
        }
        cur = gi;

        if (t == 0) {
            oi[s] = (float)cur;
            const float* __restrict__ p = xb + (size_t)cur * 3;
            op[(size_t)s * 3 + 0] = p[0];
            op[(size_t)s * 3 + 1] = p[1];
            op[(size_t)s * 3 + 2] = p[2];
        }
    }
}

extern "C" void kernel_launch(void* const* d_in, const int* in_sizes, int n_in,
                              void* d_out, int out_size, void* d_ws, size_t ws_size,
                              hipStream_t stream) {
    const float* x = (const float*)d_in[0];
    const int B = in_sizes[0] / (FPS_N * 3);

    float* out_pts = (float*)d_out;
    float* out_idx = out_pts + (size_t)B * FPS_S * 3;

    hipLaunchKernelGGL(FPSModel_80753975099708_kernel,
                       dim3(B), dim3(FPS_NT), 0, stream,
                       x, out_pts, out_idx);
}